// Round 11
// baseline (106.614 us; speedup 1.0000x reference)
//
#include <hip/hip_runtime.h>

#define ROWS 16384                 // points per side
#define PTS_TOTAL 32768
#define NSPLIT 4096                // split softmin: 1024 rowgroups x 4 col-quarters
#define NCOMB 128                  // combine/epilogue blocks

#define LOG2E 1.4426950408889634f
#define LN2   0.6931471805599453f
#define NEG_LOG2M (-12.0f)              /* -log2(4096) */
#define EPS1LNM 8.317766166719343e-4f   /* eps1 * ln(4096) */

typedef _Float16 h2 __attribute__((ext_vector_type(2)));
typedef _Float16 v8h __attribute__((ext_vector_type(8)));
typedef float f32x4 __attribute__((ext_vector_type(4)));

__device__ inline float fexp2(float x) { return __builtin_amdgcn_exp2f(x); }
__device__ inline float flog2(float x) { return __builtin_amdgcn_logf(x); }

__device__ inline unsigned fenc(float f) {
  unsigned u = __float_as_uint(f);
  return (u & 0x80000000u) ? ~u : (u | 0x80000000u);
}
__device__ inline float fdec(unsigned u) {
  return (u & 0x80000000u) ? __uint_as_float(u & 0x7fffffffu)
                           : __uint_as_float(~u);
}
__device__ inline unsigned pkh2(float a, float b) {
  h2 hv; hv.x = (_Float16)a; hv.y = (_Float16)b;
  return __builtin_bit_cast(unsigned, hv);
}
__device__ inline v8h bcv8(uint4 u) { return __builtin_bit_cast(v8h, u); }

// ---- normalized features + squared norm -----------------------------------
__device__ inline float mkv(const float* __restrict__ p, float s, float* v) {
  v[0] = p[0] * s; v[1] = p[1] * s; v[2] = p[2] * s;
  v[3] = 0.1f * fminf(fmaxf(p[3], 0.0f), 1.0f);
  v[4] = 0.1f * fminf(fmaxf(p[4], 0.0f), 1.0f);
  v[5] = 0.1f * fminf(fmaxf(p[5], 0.0f), 1.0f);
  return v[0]*v[0] + v[1]*v[1] + v[2]*v[2] + v[3]*v[3] + v[4]*v[4] + v[5]*v[5];
}

// ---- Taylor softmin evaluation (eps0 regime); M in LDS --------------------
__device__ inline float taylor_f(const float* __restrict__ M, const float* v,
                                 float q, float eps0) {
  float sc2 = 2.0f * LOG2E / eps0;
  float p[6];
#pragma unroll
  for (int d = 0; d < 6; ++d) p[d] = v[d] * sc2;
  float t1 = 0.0f;
#pragma unroll
  for (int d = 0; d < 6; ++d) t1 += p[d] * M[1 + d];
  float t2 = 0.0f;
  int kk = 7;
#pragma unroll
  for (int d = 0; d < 6; ++d) {
#pragma unroll
    for (int e = d; e < 6; ++e) {
      float coef = (d == e) ? 1.0f : 2.0f;
      t2 += coef * p[d] * p[e] * M[kk];
      kk++;
    }
  }
  float S = M[0] + LN2 * t1 + (0.5f * LN2 * LN2) * t2;
  return q - eps0 * LN2 * flog2(S);
}

// ---- single-point 28-moment vector ----------------------------------------
__device__ inline void mom28(float* acc, float wgt, const float* v) {
  acc[0] = wgt;
  int kk = 1;
#pragma unroll
  for (int d = 0; d < 6; ++d) acc[kk++] = wgt * v[d];
#pragma unroll
  for (int d = 0; d < 6; ++d) {
    float wv = wgt * v[d];
#pragma unroll
    for (int e = d; e < 6; ++e) acc[kk++] = wv * v[e];
  }
}

// ---- block reduce of 28 floats -> global dst[0..27] -----------------------
__device__ inline void red28g(float* acc, float* __restrict__ dst,
                              float (*shf)[28], int t, int wave, int lane) {
#pragma unroll
  for (int off = 32; off > 0; off >>= 1) {
#pragma unroll
    for (int k = 0; k < 28; ++k) acc[k] += __shfl_xor(acc[k], off);
  }
  if (lane == 0) {
#pragma unroll
    for (int k = 0; k < 28; ++k) shf[wave][k] = acc[k];
  }
  __syncthreads();
  if (t < 28) dst[t] = (shf[0][t] + shf[1][t]) + (shf[2][t] + shf[3][t]);
}

// ---- redundant global s/eps0 from 128 max-partial sets --------------------
__device__ inline void se_from_rmax(const unsigned* __restrict__ RMAXu,
                                    unsigned (*shu)[13], float& s, float& eps0,
                                    int t, int wave, int lane) {
  int set = t & 127;   // halves duplicate a set; max is idempotent
  unsigned e[13];
#pragma unroll
  for (int k = 0; k < 13; ++k) e[k] = RMAXu[set * 16 + k];
#pragma unroll
  for (int off = 32; off > 0; off >>= 1) {
#pragma unroll
    for (int k = 0; k < 13; ++k) {
      unsigned o = (unsigned)__shfl_xor((int)e[k], off);
      e[k] = e[k] > o ? e[k] : o;
    }
  }
  if (lane == 0) {
#pragma unroll
    for (int k = 0; k < 13; ++k) shu[wave][k] = e[k];
  }
  __syncthreads();
  unsigned mm[13];
#pragma unroll
  for (int k = 0; k < 13; ++k) {
    unsigned v0 = shu[0][k] > shu[1][k] ? shu[0][k] : shu[1][k];
    unsigned v1 = shu[2][k] > shu[3][k] ? shu[2][k] : shu[3][k];
    mm[k] = v0 > v1 ? v0 : v1;
  }
  s = 1.0f / (sqrtf(fdec(mm[0])) + 1e-6f);
  eps0 = 0.0f;
#pragma unroll
  for (int k = 0; k < 6; ++k) {
    float dd = fdec(mm[1 + k]) + fdec(mm[7 + k]);
    eps0 += dd * dd;
  }
}

// ==== K1: per-block 13 max partials (LDS-staged vectorized loads) ==========
__global__ __launch_bounds__(256) void k1_max(
    const float* __restrict__ x, const float* __restrict__ y,
    float* __restrict__ w) {
  unsigned* BARC = (unsigned*)w;
  unsigned* RMAX = (unsigned*)w + 64;
  const int t = threadIdx.x, wave = t >> 6, lane = t & 63, bx = blockIdx.x;
  if (bx == 0 && t == 0) BARC[0] = 0u;     // collector counter for KCC
  const int g0 = bx * 256;
  bool isx = g0 < ROWS;                    // 64 blocks per side; no straddle
  __shared__ float4 st[384];
  const float4* src =
      (const float4*)((isx ? x : y) + (size_t)(g0 & (ROWS - 1)) * 6);
  st[t] = src[t];
  if (t < 128) st[256 + t] = src[256 + t];
  __syncthreads();
  const float* sp = (const float*)st + t * 6;
  float d[6];
#pragma unroll
  for (int k = 0; k < 6; ++k) d[k] = sp[k];
  unsigned e[13];
  e[0] = fenc(d[0] * d[0] + d[1] * d[1] + d[2] * d[2]);
#pragma unroll
  for (int k = 0; k < 6; ++k) {
    e[1 + k] = fenc(d[k]);
    e[7 + k] = fenc(-d[k]);
  }
#pragma unroll
  for (int off = 32; off > 0; off >>= 1) {
#pragma unroll
    for (int k = 0; k < 13; ++k) {
      unsigned o = (unsigned)__shfl_xor((int)e[k], off);
      e[k] = e[k] > o ? e[k] : o;
    }
  }
  __shared__ unsigned shu[4][13];
  if (lane == 0) {
#pragma unroll
    for (int k = 0; k < 13; ++k) shu[wave][k] = e[k];
  }
  __syncthreads();
  if (t < 13) {
    unsigned v = shu[0][t];
#pragma unroll
    for (int wv = 1; wv < 4; ++wv) v = v > shu[wv][t] ? v : shu[wv][t];
    RMAX[bx * 16 + t] = v;
  }
}

// ==== K2: s/eps0 + pack AREC/Qarr + moment-1 partial =======================
__global__ __launch_bounds__(256) void k2_pack(
    const float* __restrict__ x, const float* __restrict__ y,
    float* __restrict__ w) {
  const int t = threadIdx.x, wave = t >> 6, lane = t & 63, bx = blockIdx.x;
  const unsigned* RMAX = (const unsigned*)w + 64;
  float* MOMP1 = w + 2560;
  float* base = w + 16384;
  uint4* AREC = (uint4*)base;
  float* Qarr = base + 3 * 4 * PTS_TOTAL;

  __shared__ unsigned shu[4][13];
  __shared__ float shf[4][28];
  float s, eps0;
  se_from_rmax(RMAX, shu, s, eps0, t, wave, lane);

  const int g = bx * 256 + t;
  const int side = g >> 14;
  const float* p = (side ? y : x) + (size_t)(g & (ROWS - 1)) * 6;
  float v[6]; float q = mkv(p, s, v);
  Qarr[g] = q;
  unsigned w01 = pkh2(v[0], v[1]), w23 = pkh2(v[2], v[3]), w45 = pkh2(v[4], v[5]);
  AREC[g] = (uint4){w01, w23, w45, pkh2(1.0f, 0.0f)};

  float wgt = fexp2(NEG_LOG2M - q * (LOG2E / eps0));
  float acc[28];
  mom28(acc, wgt, v);
  red28g(acc, MOMP1 + (size_t)bx * 32, shf, t, wave, lane);
}

// ==== K3: M1opp -> f1 (FG1) + moment-2 partial =============================
__global__ __launch_bounds__(256) void k3_rows1(
    const float* __restrict__ x, const float* __restrict__ y,
    float* __restrict__ w) {
  const int t = threadIdx.x, wave = t >> 6, lane = t & 63, bx = blockIdx.x;
  const unsigned* RMAX = (const unsigned*)w + 64;
  const float* MOMP1 = w + 2560;
  float* MOMP2 = w + 2560 + 4096;
  float* base = w + 16384;
  float* FG1 = base + 3 * 4 * PTS_TOTAL + PTS_TOTAL + PTS_TOTAL;  // after Qarr,FG2

  __shared__ unsigned shu[4][13];
  __shared__ float shf[4][28];
  __shared__ float M1opp[28];
  float s, eps0;
  se_from_rmax(RMAX, shu, s, eps0, t, wave, lane);

  const int g = bx * 256 + t;
  const int side = g >> 14;
  const int batch = (g >> 12) & 3;
  if (t < 28) {
    const float* mp = MOMP1 + ((size_t)((side ^ 1) * 64 + batch * 16)) * 32 + t;
    float m = 0.0f;
#pragma unroll
    for (int j = 0; j < 16; ++j) m += mp[j * 32];
    M1opp[t] = m;
  }
  __syncthreads();

  const float* p = (side ? y : x) + (size_t)(g & (ROWS - 1)) * 6;
  float v[6]; float q = mkv(p, s, v);
  float f1 = taylor_f(M1opp, v, q, eps0);
  FG1[g] = f1;
  float w2 = fexp2(NEG_LOG2M + (f1 - q) * (LOG2E / eps0));
  float acc[28];
  mom28(acc, w2, v);
  red28g(acc, MOMP2 + (size_t)bx * 32, shf, t, wave, lane);
}

// ==== K4: M2opp -> f2 (FG2) + BRECA with hs2 ===============================
__global__ __launch_bounds__(256) void k4_rows2(
    const float* __restrict__ x, const float* __restrict__ y,
    float* __restrict__ w) {
  const int t = threadIdx.x, wave = t >> 6, lane = t & 63, bx = blockIdx.x;
  const unsigned* RMAX = (const unsigned*)w + 64;
  const float* MOMP2 = w + 2560 + 4096;
  float* base = w + 16384;
  uint4* BRECA = (uint4*)base + PTS_TOTAL;
  float* Qarr = base + 3 * 4 * PTS_TOTAL;
  float* FG2 = Qarr + PTS_TOTAL;
  const float* FG1 = FG2 + PTS_TOTAL;

  __shared__ unsigned shu[4][13];
  __shared__ float M2opp[28];
  float s, eps0;
  se_from_rmax(RMAX, shu, s, eps0, t, wave, lane);

  const int g = bx * 256 + t;
  const int side = g >> 14;
  const int batch = (g >> 12) & 3;
  if (t < 28) {
    const float* mp = MOMP2 + ((size_t)((side ^ 1) * 64 + batch * 16)) * 32 + t;
    float m = 0.0f;
#pragma unroll
    for (int j = 0; j < 16; ++j) m += mp[j * 32];
    M2opp[t] = m;
  }
  __syncthreads();

  const float* p = (side ? y : x) + (size_t)(g & (ROWS - 1)) * 6;
  float v[6]; float q = mkv(p, s, v);
  float f1 = FG1[g];
  float f_t = taylor_f(M2opp, v, q, eps0);
  float f2 = 0.5f * (f1 + f_t);
  FG2[g] = f2;
  float hs2 = 0.5f * (f2 - q - EPS1LNM);
  unsigned w01 = pkh2(v[0], v[1]), w23 = pkh2(v[2], v[3]), w45 = pkh2(v[4], v[5]);
  BRECA[g] = (uint4){w01, w23, w45, pkh2(hs2, 0.0f)};
}

// ==== KMS: col-split MFMA softmin partial-max ==============================
// Block = 32 rows x 1024-col quarter, 4 waves (2 row-tiles x 2 col-halves).
// 16KB LDS stage (4 named-reg loads/thread); 8 blocks/CU resident -> 32
// waves/CU to hide panel-read latency. Writes 32 partial maxes per block.
__global__ __launch_bounds__(256) void kms(
    const uint4* __restrict__ AREC, const uint4* __restrict__ BIN,
    float* __restrict__ PMAX) {
  __shared__ uint4 Blds[1024];
  __shared__ float lm[4][16];
  const int t = threadIdx.x;
  const int w = t >> 6, lane = t & 63;
  const int l16 = lane & 15;
  const bool ldq = lane < 16;                 // quad 0 carries k=0..7
  const int bx = blockIdx.x;
  const int rowgrp = bx >> 2, q = bx & 3;
  const int grow0 = rowgrp * 32;
  const int side = grow0 >> 14;
  const int batch = (grow0 & (ROWS - 1)) >> 12;
  const int panel0 = (side ^ 1) * ROWS + batch * 4096 + q * 1024;

  // stage 1024 recs via 4 named-reg coalesced loads per thread
  const uint4* gsrc = BIN + panel0 + t;
  uint4 s0 = gsrc[0], s1 = gsrc[256], s2 = gsrc[512], s3 = gsrc[768];

  const int rt = w >> 1, ch = w & 1;          // row-tile, col-half
  uint4 z4 = (uint4){0u, 0u, 0u, 0u};
  uint4 a1u = z4;
  if (ldq) a1u = AREC[grow0 + rt * 16 + l16];
  v8h a1 = bcv8(a1u);

  Blds[t] = s0; Blds[t + 256] = s1; Blds[t + 512] = s2; Blds[t + 768] = s3;
  __syncthreads();

  f32x4 m2a = {-3.0e38f, -3.0e38f, -3.0e38f, -3.0e38f};
  const f32x4 cz = {0.0f, 0.0f, 0.0f, 0.0f};
  const int colh = ch * 512;

#pragma unroll 8
  for (int tt = 0; tt < 32; ++tt) {
    uint4 bu = z4;
    if (ldq) bu = Blds[colh + tt * 16 + l16];
    v8h b = bcv8(bu);
    f32x4 d1 = __builtin_amdgcn_mfma_f32_16x16x32_f16(a1, b, cz, 0, 0, 0);
    m2a = __builtin_elementwise_max(m2a, d1);
  }

  // reduce over the 16 col-lanes (C/D: col=lane&15, row=quad*4+reg)
#pragma unroll
  for (int off = 1; off <= 8; off <<= 1) {
#pragma unroll
    for (int r = 0; r < 4; ++r)
      m2a[r] = fmaxf(m2a[r], __shfl_xor(m2a[r], off));
  }
  if (l16 == 0) {
    int qd = lane >> 4;
#pragma unroll
    for (int r = 0; r < 4; ++r) lm[w][qd * 4 + r] = m2a[r];
  }
  __syncthreads();
  if (t < 32) {
    int rt2 = t >> 4, wi = t & 15;
    float m = fmaxf(lm[rt2 * 2][wi], lm[rt2 * 2 + 1][wi]);
    PMAX[(size_t)(grow0 + t) * 4 + q] = m;
  }
}

// ==== KBC: combine pair-3 quarters -> BRECB ================================
__global__ __launch_bounds__(256) void kbc(
    const uint4* __restrict__ AREC, const float* __restrict__ PMAX,
    const float* __restrict__ Qarr, const float* __restrict__ FG2,
    uint4* __restrict__ BRECB) {
  int g = blockIdx.x * 256 + threadIdx.x;
  float m = fmaxf(fmaxf(PMAX[(size_t)g * 4], PMAX[(size_t)g * 4 + 1]),
                  fmaxf(PMAX[(size_t)g * 4 + 2], PMAX[(size_t)g * 4 + 3]));
  float qv = Qarr[g];
  float f_t = qv - 2.0f * m;
  float fo = 0.5f * (FG2[g] + f_t);
  float hs = 0.5f * (fo - qv - EPS1LNM);
  uint4 ar = AREC[g];
  BRECB[g] = (uint4){ar.x, ar.y, ar.z, pkh2(hs, 0.0f)};
}

// ==== KCC: combine pair-4 quarters + dynamic last-block collector ==========
__global__ __launch_bounds__(256) void kcc(
    const float* __restrict__ PMAX2, const float* __restrict__ Qarr,
    float* __restrict__ PART, unsigned* __restrict__ BARC,
    float* __restrict__ out) {
  __shared__ float fred[4];
  __shared__ int lastf;
  const int t = threadIdx.x, wave = t >> 6, lane = t & 63;
  const int g = blockIdx.x * 256 + t;
  float m = fmaxf(fmaxf(PMAX2[(size_t)g * 4], PMAX2[(size_t)g * 4 + 1]),
                  fmaxf(PMAX2[(size_t)g * 4 + 2], PMAX2[(size_t)g * 4 + 3]));
  float f = Qarr[g] - 2.0f * m;
#pragma unroll
  for (int off = 32; off > 0; off >>= 1) f += __shfl_xor(f, off);
  if (lane == 0) fred[wave] = f;
  __syncthreads();
  if (t == 0) {
    float ssum = (fred[0] + fred[1]) + (fred[2] + fred[3]);
    __hip_atomic_store(&PART[blockIdx.x], ssum, __ATOMIC_RELAXED,
                       __HIP_MEMORY_SCOPE_AGENT);
    unsigned old = __hip_atomic_fetch_add(BARC, 1u, __ATOMIC_ACQ_REL,
                                          __HIP_MEMORY_SCOPE_AGENT);
    lastf = (old == (unsigned)(NCOMB - 1)) ? 1 : 0;
  }
  __syncthreads();
  if (lastf) {  // block-uniform: only the final arriver sums and writes out
    float a = 0.0f;
    if (t < NCOMB)
      a = __hip_atomic_load(&PART[t], __ATOMIC_RELAXED,
                            __HIP_MEMORY_SCOPE_AGENT);
#pragma unroll
    for (int off = 32; off > 0; off >>= 1) a += __shfl_xor(a, off);
    if (lane == 0) fred[wave] = a;
    __syncthreads();
    if (t == 0)
      out[0] = ((fred[0] + fred[1]) + (fred[2] + fred[3])) *
               (10.0f / (float)ROWS);
  }
}

extern "C" void kernel_launch(void* const* d_in, const int* in_sizes, int n_in,
                              void* d_out, int out_size, void* d_ws,
                              size_t ws_size, hipStream_t stream) {
  const float* x = (const float*)d_in[0];
  const float* y = (const float*)d_in[1];
  float* out = (float*)d_out;
  float* w = (float*)d_ws;

  unsigned* BARC = (unsigned*)w;
  float* base = w + 16384;
  uint4* AREC  = (uint4*)base;
  uint4* BRECA = AREC + PTS_TOTAL;
  uint4* BRECB = BRECA + PTS_TOTAL;
  float* Qarr  = base + 3 * 4 * PTS_TOTAL;
  float* FG2   = Qarr + PTS_TOTAL;
  float* FG1   = FG2 + PTS_TOTAL;
  float* PMAX  = FG1 + PTS_TOTAL;             // 32768*4
  float* PMAX2 = PMAX + 4 * PTS_TOTAL;        // 32768*4
  float* PART  = PMAX2 + 4 * PTS_TOTAL;       // 128

  (void)ws_size;
  k1_max<<<128, 256, 0, stream>>>(x, y, w);
  k2_pack<<<128, 256, 0, stream>>>(x, y, w);
  k3_rows1<<<128, 256, 0, stream>>>(x, y, w);
  k4_rows2<<<128, 256, 0, stream>>>(x, y, w);
  kms<<<NSPLIT, 256, 0, stream>>>(AREC, BRECA, PMAX);
  kbc<<<NCOMB, 256, 0, stream>>>(AREC, PMAX, Qarr, FG2, BRECB);
  kms<<<NSPLIT, 256, 0, stream>>>(AREC, BRECB, PMAX2);
  kcc<<<NCOMB, 256, 0, stream>>>(PMAX2, Qarr, PART, BARC, out);
}

// Round 12
// 99.429 us; speedup vs baseline: 1.0723x; 1.0723x over previous
//
#include <hip/hip_runtime.h>

#define ROWS 16384                 // points per side
#define PTS_TOTAL 32768
#define NSM_BLK 512                // softmin blocks, 64 rows each, 8 waves

#define LOG2E 1.4426950408889634f
#define LN2   0.6931471805599453f
#define NEG_LOG2M (-12.0f)              /* -log2(4096) */
#define EPS1LNM 8.317766166719343e-4f   /* eps1 * ln(4096) */

typedef _Float16 h2 __attribute__((ext_vector_type(2)));
typedef _Float16 v8h __attribute__((ext_vector_type(8)));
typedef float f32x4 __attribute__((ext_vector_type(4)));

__device__ inline float fexp2(float x) { return __builtin_amdgcn_exp2f(x); }
__device__ inline float flog2(float x) { return __builtin_amdgcn_logf(x); }

__device__ inline unsigned fenc(float f) {
  unsigned u = __float_as_uint(f);
  return (u & 0x80000000u) ? ~u : (u | 0x80000000u);
}
__device__ inline float fdec(unsigned u) {
  return (u & 0x80000000u) ? __uint_as_float(u & 0x7fffffffu)
                           : __uint_as_float(~u);
}
__device__ inline unsigned pkh2(float a, float b) {
  h2 hv; hv.x = (_Float16)a; hv.y = (_Float16)b;
  return __builtin_bit_cast(unsigned, hv);
}
__device__ inline v8h bcv8(uint4 u) { return __builtin_bit_cast(v8h, u); }

// ---- normalized features + squared norm -----------------------------------
__device__ inline float mkv(const float* __restrict__ p, float s, float* v) {
  v[0] = p[0] * s; v[1] = p[1] * s; v[2] = p[2] * s;
  v[3] = 0.1f * fminf(fmaxf(p[3], 0.0f), 1.0f);
  v[4] = 0.1f * fminf(fmaxf(p[4], 0.0f), 1.0f);
  v[5] = 0.1f * fminf(fmaxf(p[5], 0.0f), 1.0f);
  return v[0]*v[0] + v[1]*v[1] + v[2]*v[2] + v[3]*v[3] + v[4]*v[4] + v[5]*v[5];
}

// ---- Taylor softmin evaluation (eps0 regime); M in LDS --------------------
__device__ inline float taylor_f(const float* __restrict__ M, const float* v,
                                 float q, float eps0) {
  float sc2 = 2.0f * LOG2E / eps0;
  float p[6];
#pragma unroll
  for (int d = 0; d < 6; ++d) p[d] = v[d] * sc2;
  float t1 = 0.0f;
#pragma unroll
  for (int d = 0; d < 6; ++d) t1 += p[d] * M[1 + d];
  float t2 = 0.0f;
  int kk = 7;
#pragma unroll
  for (int d = 0; d < 6; ++d) {
#pragma unroll
    for (int e = d; e < 6; ++e) {
      float coef = (d == e) ? 1.0f : 2.0f;
      t2 += coef * p[d] * p[e] * M[kk];
      kk++;
    }
  }
  float S = M[0] + LN2 * t1 + (0.5f * LN2 * LN2) * t2;
  return q - eps0 * LN2 * flog2(S);
}

// ---- single-point 28-moment vector ----------------------------------------
__device__ inline void mom28(float* acc, float wgt, const float* v) {
  acc[0] = wgt;
  int kk = 1;
#pragma unroll
  for (int d = 0; d < 6; ++d) acc[kk++] = wgt * v[d];
#pragma unroll
  for (int d = 0; d < 6; ++d) {
    float wv = wgt * v[d];
#pragma unroll
    for (int e = d; e < 6; ++e) acc[kk++] = wv * v[e];
  }
}

// ---- block reduce of 28 floats -> global dst[0..27] -----------------------
__device__ inline void red28g(float* acc, float* __restrict__ dst,
                              float (*shf)[28], int t, int wave, int lane) {
#pragma unroll
  for (int off = 32; off > 0; off >>= 1) {
#pragma unroll
    for (int k = 0; k < 28; ++k) acc[k] += __shfl_xor(acc[k], off);
  }
  if (lane == 0) {
#pragma unroll
    for (int k = 0; k < 28; ++k) shf[wave][k] = acc[k];
  }
  __syncthreads();
  if (t < 28) dst[t] = (shf[0][t] + shf[1][t]) + (shf[2][t] + shf[3][t]);
}

// ---- redundant global s/eps0 from 128 max-partial sets --------------------
__device__ inline void se_from_rmax(const unsigned* __restrict__ RMAXu,
                                    unsigned (*shu)[13], float& s, float& eps0,
                                    int t, int wave, int lane) {
  int set = t & 127;   // halves duplicate a set; max is idempotent
  unsigned e[13];
#pragma unroll
  for (int k = 0; k < 13; ++k) e[k] = RMAXu[set * 16 + k];
#pragma unroll
  for (int off = 32; off > 0; off >>= 1) {
#pragma unroll
    for (int k = 0; k < 13; ++k) {
      unsigned o = (unsigned)__shfl_xor((int)e[k], off);
      e[k] = e[k] > o ? e[k] : o;
    }
  }
  if (lane == 0) {
#pragma unroll
    for (int k = 0; k < 13; ++k) shu[wave][k] = e[k];
  }
  __syncthreads();
  unsigned mm[13];
#pragma unroll
  for (int k = 0; k < 13; ++k) {
    unsigned v0 = shu[0][k] > shu[1][k] ? shu[0][k] : shu[1][k];
    unsigned v1 = shu[2][k] > shu[3][k] ? shu[2][k] : shu[3][k];
    mm[k] = v0 > v1 ? v0 : v1;
  }
  s = 1.0f / (sqrtf(fdec(mm[0])) + 1e-6f);
  eps0 = 0.0f;
#pragma unroll
  for (int k = 0; k < 6; ++k) {
    float dd = fdec(mm[1 + k]) + fdec(mm[7 + k]);
    eps0 += dd * dd;
  }
}

// ==== K1: per-block 13 max partials (LDS-staged vectorized loads) ==========
__global__ __launch_bounds__(256) void k1_max(
    const float* __restrict__ x, const float* __restrict__ y,
    float* __restrict__ w) {
  unsigned* BARC = (unsigned*)w;
  unsigned* RMAX = (unsigned*)w + 64;
  const int t = threadIdx.x, wave = t >> 6, lane = t & 63, bx = blockIdx.x;
  if (bx == 0 && t == 0) BARC[0] = 0u;     // collector counter for KC
  const int g0 = bx * 256;
  bool isx = g0 < ROWS;                    // 64 blocks per side; no straddle
  __shared__ float4 st[384];
  const float4* src =
      (const float4*)((isx ? x : y) + (size_t)(g0 & (ROWS - 1)) * 6);
  st[t] = src[t];
  if (t < 128) st[256 + t] = src[256 + t];
  __syncthreads();
  const float* sp = (const float*)st + t * 6;
  float d[6];
#pragma unroll
  for (int k = 0; k < 6; ++k) d[k] = sp[k];
  unsigned e[13];
  e[0] = fenc(d[0] * d[0] + d[1] * d[1] + d[2] * d[2]);
#pragma unroll
  for (int k = 0; k < 6; ++k) {
    e[1 + k] = fenc(d[k]);
    e[7 + k] = fenc(-d[k]);
  }
#pragma unroll
  for (int off = 32; off > 0; off >>= 1) {
#pragma unroll
    for (int k = 0; k < 13; ++k) {
      unsigned o = (unsigned)__shfl_xor((int)e[k], off);
      e[k] = e[k] > o ? e[k] : o;
    }
  }
  __shared__ unsigned shu[4][13];
  if (lane == 0) {
#pragma unroll
    for (int k = 0; k < 13; ++k) shu[wave][k] = e[k];
  }
  __syncthreads();
  if (t < 13) {
    unsigned v = shu[0][t];
#pragma unroll
    for (int wv = 1; wv < 4; ++wv) v = v > shu[wv][t] ? v : shu[wv][t];
    RMAX[bx * 16 + t] = v;
  }
}

// ==== K2: s/eps0 + pack AREC/Qarr + moment-1 partial =======================
__global__ __launch_bounds__(256) void k2_pack(
    const float* __restrict__ x, const float* __restrict__ y,
    float* __restrict__ w) {
  const int t = threadIdx.x, wave = t >> 6, lane = t & 63, bx = blockIdx.x;
  const unsigned* RMAX = (const unsigned*)w + 64;
  float* MOMP1 = w + 2560;
  float* base = w + 16384;
  uint4* AREC = (uint4*)base;
  float* Qarr = base + 3 * 4 * PTS_TOTAL;

  __shared__ unsigned shu[4][13];
  __shared__ float shf[4][28];
  float s, eps0;
  se_from_rmax(RMAX, shu, s, eps0, t, wave, lane);

  const int g = bx * 256 + t;
  const int side = g >> 14;
  const float* p = (side ? y : x) + (size_t)(g & (ROWS - 1)) * 6;
  float v[6]; float q = mkv(p, s, v);
  Qarr[g] = q;
  unsigned w01 = pkh2(v[0], v[1]), w23 = pkh2(v[2], v[3]), w45 = pkh2(v[4], v[5]);
  AREC[g] = (uint4){w01, w23, w45, pkh2(1.0f, 0.0f)};

  float wgt = fexp2(NEG_LOG2M - q * (LOG2E / eps0));
  float acc[28];
  mom28(acc, wgt, v);
  red28g(acc, MOMP1 + (size_t)bx * 32, shf, t, wave, lane);
}

// ==== K3: M1opp -> f1 (FG1) + moment-2 partial =============================
__global__ __launch_bounds__(256) void k3_rows1(
    const float* __restrict__ x, const float* __restrict__ y,
    float* __restrict__ w) {
  const int t = threadIdx.x, wave = t >> 6, lane = t & 63, bx = blockIdx.x;
  const unsigned* RMAX = (const unsigned*)w + 64;
  const float* MOMP1 = w + 2560;
  float* MOMP2 = w + 2560 + 4096;
  float* base = w + 16384;
  float* FG1 = base + 3 * 4 * PTS_TOTAL + PTS_TOTAL + PTS_TOTAL;  // after Qarr,FG2

  __shared__ unsigned shu[4][13];
  __shared__ float shf[4][28];
  __shared__ float M1opp[28];
  float s, eps0;
  se_from_rmax(RMAX, shu, s, eps0, t, wave, lane);

  const int g = bx * 256 + t;
  const int side = g >> 14;
  const int batch = (g >> 12) & 3;
  if (t < 28) {
    const float* mp = MOMP1 + ((size_t)((side ^ 1) * 64 + batch * 16)) * 32 + t;
    float m = 0.0f;
#pragma unroll
    for (int j = 0; j < 16; ++j) m += mp[j * 32];
    M1opp[t] = m;
  }
  __syncthreads();

  const float* p = (side ? y : x) + (size_t)(g & (ROWS - 1)) * 6;
  float v[6]; float q = mkv(p, s, v);
  float f1 = taylor_f(M1opp, v, q, eps0);
  FG1[g] = f1;
  float w2 = fexp2(NEG_LOG2M + (f1 - q) * (LOG2E / eps0));
  float acc[28];
  mom28(acc, w2, v);
  red28g(acc, MOMP2 + (size_t)bx * 32, shf, t, wave, lane);
}

// ==== K4: M2opp -> f2 (FG2) + BRECA with hs2 ===============================
__global__ __launch_bounds__(256) void k4_rows2(
    const float* __restrict__ x, const float* __restrict__ y,
    float* __restrict__ w) {
  const int t = threadIdx.x, wave = t >> 6, lane = t & 63, bx = blockIdx.x;
  const unsigned* RMAX = (const unsigned*)w + 64;
  const float* MOMP2 = w + 2560 + 4096;
  float* base = w + 16384;
  uint4* BRECA = (uint4*)base + PTS_TOTAL;
  float* Qarr = base + 3 * 4 * PTS_TOTAL;
  float* FG2 = Qarr + PTS_TOTAL;
  const float* FG1 = FG2 + PTS_TOTAL;

  __shared__ unsigned shu[4][13];
  __shared__ float M2opp[28];
  float s, eps0;
  se_from_rmax(RMAX, shu, s, eps0, t, wave, lane);

  const int g = bx * 256 + t;
  const int side = g >> 14;
  const int batch = (g >> 12) & 3;
  if (t < 28) {
    const float* mp = MOMP2 + ((size_t)((side ^ 1) * 64 + batch * 16)) * 32 + t;
    float m = 0.0f;
#pragma unroll
    for (int j = 0; j < 16; ++j) m += mp[j * 32];
    M2opp[t] = m;
  }
  __syncthreads();

  const float* p = (side ? y : x) + (size_t)(g & (ROWS - 1)) * 6;
  float v[6]; float q = mkv(p, s, v);
  float f1 = FG1[g];
  float f_t = taylor_f(M2opp, v, q, eps0);
  float f2 = 0.5f * (f1 + f_t);
  FG2[g] = f2;
  float hs2 = 0.5f * (f2 - q - EPS1LNM);
  unsigned w01 = pkh2(v[0], v[1]), w23 = pkh2(v[2], v[3]), w45 = pkh2(v[4], v[5]);
  BRECA[g] = (uint4){w01, w23, w45, pkh2(hs2, 0.0f)};
}

// ---- XCD-aware remap (T1): physical bx%8 = XCD (round-robin model). All 64
// blocks consuming one 512KB B-panel land on one XCD -> panel fetched into
// that XCD's L2 once; cross-XCD/L3 panel traffic 32MB -> 4MB per pass.
__device__ inline int xcd_rowgrp(int bx) {
  return (bx & 7) * 64 + (bx >> 3);          // 512 = 64 x 8, bijective
}

// ---- LDS-staged MFMA softmin: 64 rows/group, 8 waves, whole 64KB B panel
// staged in LDS once (named regs, bulk-issued loads), then MFMA loop reads
// LDS only. Wave w: col quarter (w&3), row half (w>>2). Row-max valid t<64.
__device__ inline float softmax_max64L(int grow0,
                                       const uint4* __restrict__ AREC,
                                       const uint4* __restrict__ BIN,
                                       uint4* __restrict__ Blds,
                                       float (*lm)[32]) {
  int t = threadIdx.x;
  int w = t >> 6, lane = t & 63;
  int l16 = lane & 15;
  bool ldq = lane < 16;                       // quad 0 carries k=0..7
  int side = grow0 >> 14;
  int batch = (grow0 & (ROWS - 1)) >> 12;
  int panel0 = (side ^ 1) * ROWS + batch * 4096;

  // ---- stage B panel: each wave 512 recs (8KB) via 8 bulk 1KB loads ----
  const uint4* gsrc = BIN + panel0 + w * 512 + lane;
  uint4* ldst = Blds + w * 512 + lane;
  uint4 s0 = gsrc[0],   s1 = gsrc[64],  s2 = gsrc[128], s3 = gsrc[192];
  uint4 s4 = gsrc[256], s5 = gsrc[320], s6 = gsrc[384], s7 = gsrc[448];

  // A fragments (global; independent of staging)
  uint4 z4 = (uint4){0u, 0u, 0u, 0u};
  uint4 a1u = z4, a2u = z4;
  int arow = grow0 + (w >> 2) * 32;
  if (ldq) {
    a1u = AREC[arow + l16];
    a2u = AREC[arow + 16 + l16];
  }
  v8h a1 = bcv8(a1u), a2 = bcv8(a2u);

  ldst[0] = s0;   ldst[64] = s1;  ldst[128] = s2; ldst[192] = s3;
  ldst[256] = s4; ldst[320] = s5; ldst[384] = s6; ldst[448] = s7;
  __syncthreads();

  f32x4 m2a = {-3.0e38f, -3.0e38f, -3.0e38f, -3.0e38f};
  f32x4 m2b = m2a;
  const f32x4 cz = {0.0f, 0.0f, 0.0f, 0.0f};
  const int colq = (w & 3) * 1024;

#pragma unroll 8
  for (int tt = 0; tt < 64; ++tt) {
    uint4 bu = z4;
    if (ldq) bu = Blds[colq + tt * 16 + l16];
    v8h b = bcv8(bu);
    f32x4 d1 = __builtin_amdgcn_mfma_f32_16x16x32_f16(a1, b, cz, 0, 0, 0);
    f32x4 d2 = __builtin_amdgcn_mfma_f32_16x16x32_f16(a2, b, cz, 0, 0, 0);
    m2a = __builtin_elementwise_max(m2a, d1);
    m2b = __builtin_elementwise_max(m2b, d2);
  }

  // reduce over the 16 col-lanes (C/D: col=lane&15, row=quad*4+reg)
#pragma unroll
  for (int off = 1; off <= 8; off <<= 1) {
#pragma unroll
    for (int r = 0; r < 4; ++r) {
      m2a[r] = fmaxf(m2a[r], __shfl_xor(m2a[r], off));
      m2b[r] = fmaxf(m2b[r], __shfl_xor(m2b[r], off));
    }
  }
  if (l16 == 0) {
    int qd = lane >> 4;
#pragma unroll
    for (int r = 0; r < 4; ++r) {
      lm[w][qd * 4 + r] = m2a[r];
      lm[w][16 + qd * 4 + r] = m2b[r];
    }
  }
  __syncthreads();
  float m = 0.0f;
  if (t < 64) {
    int half4 = (t >> 5) * 4, r32 = t & 31;
    m = fmaxf(fmaxf(lm[half4][r32], lm[half4 + 1][r32]),
              fmaxf(lm[half4 + 2][r32], lm[half4 + 3][r32]));
  }
  return m;
}

// ==== KB: eps1 softmin pair-3 -> BRECB =====================================
__global__ __launch_bounds__(512) void kb_sm1(
    const uint4* __restrict__ AREC, const uint4* __restrict__ BIN,
    uint4* __restrict__ BOUT, const float* __restrict__ Qarr,
    const float* __restrict__ FG2) {
  __shared__ uint4 Blds[4096];
  __shared__ float lm[8][32];
  int t = threadIdx.x;
  int grow0 = xcd_rowgrp(blockIdx.x) * 64;
  // prefetch epilogue operands; latency hides under staging + MFMA loop
  float qv = 0.0f, fprev = 0.0f;
  uint4 ar = (uint4){0u, 0u, 0u, 0u};
  if (t < 64) {
    int gg = grow0 + t;
    qv = Qarr[gg];
    fprev = FG2[gg];
    ar = AREC[gg];
  }
  float m = softmax_max64L(grow0, AREC, BIN, Blds, lm);
  if (t < 64) {
    float f_t = qv - 2.0f * m;
    float fo = 0.5f * (fprev + f_t);
    float hs = 0.5f * (fo - qv - EPS1LNM);
    BOUT[grow0 + t] = (uint4){ar.x, ar.y, ar.z, pkh2(hs, 0.0f)};
  }
}

// ==== KC: eps1 softmin pair-4 + dynamic last-block collector ===============
__global__ __launch_bounds__(512) void kc_sm2(
    const uint4* __restrict__ AREC, const uint4* __restrict__ BIN,
    const float* __restrict__ Qarr, float* __restrict__ PART,
    unsigned* __restrict__ BARC, float* __restrict__ out) {
  __shared__ uint4 Blds[4096];
  __shared__ float lm[8][32];
  __shared__ float fsh[64];
  __shared__ float fred[8];
  __shared__ int lastf;
  int t = threadIdx.x;
  int wave = t >> 6, lane = t & 63;
  int grow0 = xcd_rowgrp(blockIdx.x) * 64;
  float qv = 0.0f;
  if (t < 64) qv = Qarr[grow0 + t];
  float m = softmax_max64L(grow0, AREC, BIN, Blds, lm);
  if (t < 64) fsh[t] = qv - 2.0f * m;
  __syncthreads();
  if (t == 0) {
    float ssum = 0.0f;
#pragma unroll
    for (int k = 0; k < 64; ++k) ssum += fsh[k];
    __hip_atomic_store(&PART[blockIdx.x], ssum, __ATOMIC_RELAXED,
                       __HIP_MEMORY_SCOPE_AGENT);
    unsigned old = __hip_atomic_fetch_add(BARC, 1u, __ATOMIC_ACQ_REL,
                                          __HIP_MEMORY_SCOPE_AGENT);
    lastf = (old == (unsigned)(NSM_BLK - 1)) ? 1 : 0;
  }
  __syncthreads();
  if (lastf) {  // block-uniform: only the final arriver sums and writes out
    float a = __hip_atomic_load(&PART[t], __ATOMIC_RELAXED,
                                __HIP_MEMORY_SCOPE_AGENT);
#pragma unroll
    for (int off = 32; off > 0; off >>= 1) a += __shfl_xor(a, off);
    if (lane == 0) fred[wave] = a;
    __syncthreads();
    if (t == 0) {
      float s8 = 0.0f;
#pragma unroll
      for (int k = 0; k < 8; ++k) s8 += fred[k];
      out[0] = s8 * (10.0f / (float)ROWS);
    }
  }
}

extern "C" void kernel_launch(void* const* d_in, const int* in_sizes, int n_in,
                              void* d_out, int out_size, void* d_ws,
                              size_t ws_size, hipStream_t stream) {
  const float* x = (const float*)d_in[0];
  const float* y = (const float*)d_in[1];
  float* out = (float*)d_out;
  float* w = (float*)d_ws;

  unsigned* BARC = (unsigned*)w;
  float* base = w + 16384;
  uint4* AREC  = (uint4*)base;
  uint4* BRECA = AREC + PTS_TOTAL;
  uint4* BRECB = BRECA + PTS_TOTAL;
  float* Qarr  = base + 3 * 4 * PTS_TOTAL;
  float* FG2   = Qarr + PTS_TOTAL;
  float* FG1   = FG2 + PTS_TOTAL;
  float* PART  = FG1 + PTS_TOTAL;

  (void)ws_size;
  k1_max<<<128, 256, 0, stream>>>(x, y, w);
  k2_pack<<<128, 256, 0, stream>>>(x, y, w);
  k3_rows1<<<128, 256, 0, stream>>>(x, y, w);
  k4_rows2<<<128, 256, 0, stream>>>(x, y, w);
  kb_sm1<<<NSM_BLK, 512, 0, stream>>>(AREC, BRECA, BRECB, Qarr, FG2);
  kc_sm2<<<NSM_BLK, 512, 0, stream>>>(AREC, BRECB, Qarr, PART, BARC, out);
}

// Round 13
// 97.227 us; speedup vs baseline: 1.0965x; 1.0226x over previous
//
#include <hip/hip_runtime.h>

#define ROWS 16384                 // points per side
#define PTS_TOTAL 32768
#define NSM_BLK 256                // softmin blocks, 128 rows each, 8 waves

#define LOG2E 1.4426950408889634f
#define LN2   0.6931471805599453f
#define NEG_LOG2M (-12.0f)              /* -log2(4096) */
#define EPS1LNM 8.317766166719343e-4f   /* eps1 * ln(4096) */

typedef _Float16 h2 __attribute__((ext_vector_type(2)));
typedef _Float16 v8h __attribute__((ext_vector_type(8)));
typedef float f32x4 __attribute__((ext_vector_type(4)));

__device__ inline float fexp2(float x) { return __builtin_amdgcn_exp2f(x); }
__device__ inline float flog2(float x) { return __builtin_amdgcn_logf(x); }

__device__ inline unsigned fenc(float f) {
  unsigned u = __float_as_uint(f);
  return (u & 0x80000000u) ? ~u : (u | 0x80000000u);
}
__device__ inline float fdec(unsigned u) {
  return (u & 0x80000000u) ? __uint_as_float(u & 0x7fffffffu)
                           : __uint_as_float(~u);
}
__device__ inline unsigned pkh2(float a, float b) {
  h2 hv; hv.x = (_Float16)a; hv.y = (_Float16)b;
  return __builtin_bit_cast(unsigned, hv);
}
__device__ inline v8h bcv8(uint4 u) { return __builtin_bit_cast(v8h, u); }

// ---- normalized features + squared norm -----------------------------------
__device__ inline float mkv(const float* __restrict__ p, float s, float* v) {
  v[0] = p[0] * s; v[1] = p[1] * s; v[2] = p[2] * s;
  v[3] = 0.1f * fminf(fmaxf(p[3], 0.0f), 1.0f);
  v[4] = 0.1f * fminf(fmaxf(p[4], 0.0f), 1.0f);
  v[5] = 0.1f * fminf(fmaxf(p[5], 0.0f), 1.0f);
  return v[0]*v[0] + v[1]*v[1] + v[2]*v[2] + v[3]*v[3] + v[4]*v[4] + v[5]*v[5];
}

// ---- Taylor softmin evaluation (eps0 regime); M in LDS --------------------
__device__ inline float taylor_f(const float* __restrict__ M, const float* v,
                                 float q, float eps0) {
  float sc2 = 2.0f * LOG2E / eps0;
  float p[6];
#pragma unroll
  for (int d = 0; d < 6; ++d) p[d] = v[d] * sc2;
  float t1 = 0.0f;
#pragma unroll
  for (int d = 0; d < 6; ++d) t1 += p[d] * M[1 + d];
  float t2 = 0.0f;
  int kk = 7;
#pragma unroll
  for (int d = 0; d < 6; ++d) {
#pragma unroll
    for (int e = d; e < 6; ++e) {
      float coef = (d == e) ? 1.0f : 2.0f;
      t2 += coef * p[d] * p[e] * M[kk];
      kk++;
    }
  }
  float S = M[0] + LN2 * t1 + (0.5f * LN2 * LN2) * t2;
  return q - eps0 * LN2 * flog2(S);
}

// ---- single-point 28-moment vector ----------------------------------------
__device__ inline void mom28(float* acc, float wgt, const float* v) {
  acc[0] = wgt;
  int kk = 1;
#pragma unroll
  for (int d = 0; d < 6; ++d) acc[kk++] = wgt * v[d];
#pragma unroll
  for (int d = 0; d < 6; ++d) {
    float wv = wgt * v[d];
#pragma unroll
    for (int e = d; e < 6; ++e) acc[kk++] = wv * v[e];
  }
}

// ---- block reduce of 28 floats -> global dst[0..27] -----------------------
__device__ inline void red28g(float* acc, float* __restrict__ dst,
                              float (*shf)[28], int t, int wave, int lane) {
#pragma unroll
  for (int off = 32; off > 0; off >>= 1) {
#pragma unroll
    for (int k = 0; k < 28; ++k) acc[k] += __shfl_xor(acc[k], off);
  }
  if (lane == 0) {
#pragma unroll
    for (int k = 0; k < 28; ++k) shf[wave][k] = acc[k];
  }
  __syncthreads();
  if (t < 28) dst[t] = (shf[0][t] + shf[1][t]) + (shf[2][t] + shf[3][t]);
}

// ---- redundant global s/eps0 from 128 max-partial sets --------------------
__device__ inline void se_from_rmax(const unsigned* __restrict__ RMAXu,
                                    unsigned (*shu)[13], float& s, float& eps0,
                                    int t, int wave, int lane) {
  int set = t & 127;   // halves duplicate a set; max is idempotent
  unsigned e[13];
#pragma unroll
  for (int k = 0; k < 13; ++k) e[k] = RMAXu[set * 16 + k];
#pragma unroll
  for (int off = 32; off > 0; off >>= 1) {
#pragma unroll
    for (int k = 0; k < 13; ++k) {
      unsigned o = (unsigned)__shfl_xor((int)e[k], off);
      e[k] = e[k] > o ? e[k] : o;
    }
  }
  if (lane == 0) {
#pragma unroll
    for (int k = 0; k < 13; ++k) shu[wave][k] = e[k];
  }
  __syncthreads();
  unsigned mm[13];
#pragma unroll
  for (int k = 0; k < 13; ++k) {
    unsigned v0 = shu[0][k] > shu[1][k] ? shu[0][k] : shu[1][k];
    unsigned v1 = shu[2][k] > shu[3][k] ? shu[2][k] : shu[3][k];
    mm[k] = v0 > v1 ? v0 : v1;
  }
  s = 1.0f / (sqrtf(fdec(mm[0])) + 1e-6f);
  eps0 = 0.0f;
#pragma unroll
  for (int k = 0; k < 6; ++k) {
    float dd = fdec(mm[1 + k]) + fdec(mm[7 + k]);
    eps0 += dd * dd;
  }
}

// ==== K1: per-block 13 max partials (LDS-staged vectorized loads) ==========
__global__ __launch_bounds__(256) void k1_max(
    const float* __restrict__ x, const float* __restrict__ y,
    float* __restrict__ w) {
  unsigned* BARC = (unsigned*)w;
  unsigned* RMAX = (unsigned*)w + 64;
  const int t = threadIdx.x, wave = t >> 6, lane = t & 63, bx = blockIdx.x;
  if (bx == 0 && t == 0) BARC[0] = 0u;     // collector counter for KC
  const int g0 = bx * 256;
  bool isx = g0 < ROWS;                    // 64 blocks per side; no straddle
  __shared__ float4 st[384];
  const float4* src =
      (const float4*)((isx ? x : y) + (size_t)(g0 & (ROWS - 1)) * 6);
  st[t] = src[t];
  if (t < 128) st[256 + t] = src[256 + t];
  __syncthreads();
  const float* sp = (const float*)st + t * 6;
  float d[6];
#pragma unroll
  for (int k = 0; k < 6; ++k) d[k] = sp[k];
  unsigned e[13];
  e[0] = fenc(d[0] * d[0] + d[1] * d[1] + d[2] * d[2]);
#pragma unroll
  for (int k = 0; k < 6; ++k) {
    e[1 + k] = fenc(d[k]);
    e[7 + k] = fenc(-d[k]);
  }
#pragma unroll
  for (int off = 32; off > 0; off >>= 1) {
#pragma unroll
    for (int k = 0; k < 13; ++k) {
      unsigned o = (unsigned)__shfl_xor((int)e[k], off);
      e[k] = e[k] > o ? e[k] : o;
    }
  }
  __shared__ unsigned shu[4][13];
  if (lane == 0) {
#pragma unroll
    for (int k = 0; k < 13; ++k) shu[wave][k] = e[k];
  }
  __syncthreads();
  if (t < 13) {
    unsigned v = shu[0][t];
#pragma unroll
    for (int wv = 1; wv < 4; ++wv) v = v > shu[wv][t] ? v : shu[wv][t];
    RMAX[bx * 16 + t] = v;
  }
}

// ==== K2: s/eps0 + pack AREC/Qarr + moment-1 partial =======================
__global__ __launch_bounds__(256) void k2_pack(
    const float* __restrict__ x, const float* __restrict__ y,
    float* __restrict__ w) {
  const int t = threadIdx.x, wave = t >> 6, lane = t & 63, bx = blockIdx.x;
  const unsigned* RMAX = (const unsigned*)w + 64;
  float* MOMP1 = w + 2560;
  float* base = w + 16384;
  uint4* AREC = (uint4*)base;
  float* Qarr = base + 3 * 4 * PTS_TOTAL;

  __shared__ unsigned shu[4][13];
  __shared__ float shf[4][28];
  float s, eps0;
  se_from_rmax(RMAX, shu, s, eps0, t, wave, lane);

  const int g = bx * 256 + t;
  const int side = g >> 14;
  const float* p = (side ? y : x) + (size_t)(g & (ROWS - 1)) * 6;
  float v[6]; float q = mkv(p, s, v);
  Qarr[g] = q;
  unsigned w01 = pkh2(v[0], v[1]), w23 = pkh2(v[2], v[3]), w45 = pkh2(v[4], v[5]);
  AREC[g] = (uint4){w01, w23, w45, pkh2(1.0f, 0.0f)};

  float wgt = fexp2(NEG_LOG2M - q * (LOG2E / eps0));
  float acc[28];
  mom28(acc, wgt, v);
  red28g(acc, MOMP1 + (size_t)bx * 32, shf, t, wave, lane);
}

// ==== K3: M1opp -> f1 (FG1) + moment-2 partial =============================
__global__ __launch_bounds__(256) void k3_rows1(
    const float* __restrict__ x, const float* __restrict__ y,
    float* __restrict__ w) {
  const int t = threadIdx.x, wave = t >> 6, lane = t & 63, bx = blockIdx.x;
  const unsigned* RMAX = (const unsigned*)w + 64;
  const float* MOMP1 = w + 2560;
  float* MOMP2 = w + 2560 + 4096;
  float* base = w + 16384;
  float* FG1 = base + 3 * 4 * PTS_TOTAL + PTS_TOTAL + PTS_TOTAL;  // after Qarr,FG2

  __shared__ unsigned shu[4][13];
  __shared__ float shf[4][28];
  __shared__ float M1opp[28];
  float s, eps0;
  se_from_rmax(RMAX, shu, s, eps0, t, wave, lane);

  const int g = bx * 256 + t;
  const int side = g >> 14;
  const int batch = (g >> 12) & 3;
  if (t < 28) {
    const float* mp = MOMP1 + ((size_t)((side ^ 1) * 64 + batch * 16)) * 32 + t;
    float m = 0.0f;
#pragma unroll
    for (int j = 0; j < 16; ++j) m += mp[j * 32];
    M1opp[t] = m;
  }
  __syncthreads();

  const float* p = (side ? y : x) + (size_t)(g & (ROWS - 1)) * 6;
  float v[6]; float q = mkv(p, s, v);
  float f1 = taylor_f(M1opp, v, q, eps0);
  FG1[g] = f1;
  float w2 = fexp2(NEG_LOG2M + (f1 - q) * (LOG2E / eps0));
  float acc[28];
  mom28(acc, w2, v);
  red28g(acc, MOMP2 + (size_t)bx * 32, shf, t, wave, lane);
}

// ==== K4: M2opp -> f2 (FG2) + BRECA with hs2 ===============================
__global__ __launch_bounds__(256) void k4_rows2(
    const float* __restrict__ x, const float* __restrict__ y,
    float* __restrict__ w) {
  const int t = threadIdx.x, wave = t >> 6, lane = t & 63, bx = blockIdx.x;
  const unsigned* RMAX = (const unsigned*)w + 64;
  const float* MOMP2 = w + 2560 + 4096;
  float* base = w + 16384;
  uint4* BRECA = (uint4*)base + PTS_TOTAL;
  float* Qarr = base + 3 * 4 * PTS_TOTAL;
  float* FG2 = Qarr + PTS_TOTAL;
  const float* FG1 = FG2 + PTS_TOTAL;

  __shared__ unsigned shu[4][13];
  __shared__ float M2opp[28];
  float s, eps0;
  se_from_rmax(RMAX, shu, s, eps0, t, wave, lane);

  const int g = bx * 256 + t;
  const int side = g >> 14;
  const int batch = (g >> 12) & 3;
  if (t < 28) {
    const float* mp = MOMP2 + ((size_t)((side ^ 1) * 64 + batch * 16)) * 32 + t;
    float m = 0.0f;
#pragma unroll
    for (int j = 0; j < 16; ++j) m += mp[j * 32];
    M2opp[t] = m;
  }
  __syncthreads();

  const float* p = (side ? y : x) + (size_t)(g & (ROWS - 1)) * 6;
  float v[6]; float q = mkv(p, s, v);
  float f1 = FG1[g];
  float f_t = taylor_f(M2opp, v, q, eps0);
  float f2 = 0.5f * (f1 + f_t);
  FG2[g] = f2;
  float hs2 = 0.5f * (f2 - q - EPS1LNM);
  unsigned w01 = pkh2(v[0], v[1]), w23 = pkh2(v[2], v[3]), w45 = pkh2(v[4], v[5]);
  BRECA[g] = (uint4){w01, w23, w45, pkh2(hs2, 0.0f)};
}

// ---- XCD-aware remap: 256 = 32 x 8; all 32 blocks sharing one panel on one
// XCD under the round-robin model (kept from R12; null there but harmless).
__device__ inline int xcd_rowgrp(int bx) {
  return (bx & 7) * 32 + (bx >> 3);
}

// ---- LDS-staged MFMA softmin: 128 rows/group, 8 waves, whole 64KB B panel
// staged once -> HALF the aggregate staged bytes vs 64-row blocks (16MB/pass).
// Wave w: col quarter (w&3), row half (w>>2) with 4 A-frags (64 rows).
// Row-max valid for t<128.
__device__ inline float softmax_max128L(int grow0,
                                        const uint4* __restrict__ AREC,
                                        const uint4* __restrict__ BIN,
                                        uint4* __restrict__ Blds,
                                        float (*lm)[64]) {
  int t = threadIdx.x;
  int w = t >> 6, lane = t & 63;
  int l16 = lane & 15;
  bool ldq = lane < 16;                       // quad 0 carries k=0..7
  int side = grow0 >> 14;
  int batch = (grow0 & (ROWS - 1)) >> 12;
  int panel0 = (side ^ 1) * ROWS + batch * 4096;

  // ---- stage B panel: each wave 512 recs (8KB) via 8 bulk 1KB loads ----
  const uint4* gsrc = BIN + panel0 + w * 512 + lane;
  uint4* ldst = Blds + w * 512 + lane;
  uint4 s0 = gsrc[0],   s1 = gsrc[64],  s2 = gsrc[128], s3 = gsrc[192];
  uint4 s4 = gsrc[256], s5 = gsrc[320], s6 = gsrc[384], s7 = gsrc[448];

  // A fragments: 4 x 16-row tiles covering this wave's 64-row half
  uint4 z4 = (uint4){0u, 0u, 0u, 0u};
  uint4 a0u = z4, a1u = z4, a2u = z4, a3u = z4;
  int arow = grow0 + (w >> 2) * 64;
  if (ldq) {
    a0u = AREC[arow + l16];
    a1u = AREC[arow + 16 + l16];
    a2u = AREC[arow + 32 + l16];
    a3u = AREC[arow + 48 + l16];
  }
  v8h a0 = bcv8(a0u), a1 = bcv8(a1u), a2 = bcv8(a2u), a3 = bcv8(a3u);

  ldst[0] = s0;   ldst[64] = s1;  ldst[128] = s2; ldst[192] = s3;
  ldst[256] = s4; ldst[320] = s5; ldst[384] = s6; ldst[448] = s7;
  __syncthreads();

  f32x4 m0 = {-3.0e38f, -3.0e38f, -3.0e38f, -3.0e38f};
  f32x4 m1 = m0, m2 = m0, m3 = m0;
  const f32x4 cz = {0.0f, 0.0f, 0.0f, 0.0f};
  const int colq = (w & 3) * 1024;

#pragma unroll 8
  for (int tt = 0; tt < 64; ++tt) {
    uint4 bu = z4;
    if (ldq) bu = Blds[colq + tt * 16 + l16];
    v8h b = bcv8(bu);
    f32x4 d0 = __builtin_amdgcn_mfma_f32_16x16x32_f16(a0, b, cz, 0, 0, 0);
    f32x4 d1 = __builtin_amdgcn_mfma_f32_16x16x32_f16(a1, b, cz, 0, 0, 0);
    f32x4 d2 = __builtin_amdgcn_mfma_f32_16x16x32_f16(a2, b, cz, 0, 0, 0);
    f32x4 d3 = __builtin_amdgcn_mfma_f32_16x16x32_f16(a3, b, cz, 0, 0, 0);
    m0 = __builtin_elementwise_max(m0, d0);
    m1 = __builtin_elementwise_max(m1, d1);
    m2 = __builtin_elementwise_max(m2, d2);
    m3 = __builtin_elementwise_max(m3, d3);
  }

  // reduce over the 16 col-lanes (C/D: col=lane&15, row=quad*4+reg)
#pragma unroll
  for (int off = 1; off <= 8; off <<= 1) {
#pragma unroll
    for (int r = 0; r < 4; ++r) {
      m0[r] = fmaxf(m0[r], __shfl_xor(m0[r], off));
      m1[r] = fmaxf(m1[r], __shfl_xor(m1[r], off));
      m2[r] = fmaxf(m2[r], __shfl_xor(m2[r], off));
      m3[r] = fmaxf(m3[r], __shfl_xor(m3[r], off));
    }
  }
  if (l16 == 0) {
    int qd = lane >> 4;
#pragma unroll
    for (int r = 0; r < 4; ++r) {
      lm[w][qd * 4 + r]      = m0[r];
      lm[w][16 + qd * 4 + r] = m1[r];
      lm[w][32 + qd * 4 + r] = m2[r];
      lm[w][48 + qd * 4 + r] = m3[r];
    }
  }
  __syncthreads();
  float m = 0.0f;
  if (t < 128) {
    int half4 = (t >> 6) * 4, lr = t & 63;   // waves h*4..h*4+3 hold half h
    m = fmaxf(fmaxf(lm[half4][lr], lm[half4 + 1][lr]),
              fmaxf(lm[half4 + 2][lr], lm[half4 + 3][lr]));
  }
  return m;
}

// ==== KB: eps1 softmin pair-3 -> BRECB =====================================
__global__ __launch_bounds__(512) void kb_sm1(
    const uint4* __restrict__ AREC, const uint4* __restrict__ BIN,
    uint4* __restrict__ BOUT, const float* __restrict__ Qarr,
    const float* __restrict__ FG2) {
  __shared__ uint4 Blds[4096];
  __shared__ float lm[8][64];
  int t = threadIdx.x;
  int grow0 = xcd_rowgrp(blockIdx.x) * 128;
  // prefetch epilogue operands; latency hides under staging + MFMA loop
  float qv = 0.0f, fprev = 0.0f;
  uint4 ar = (uint4){0u, 0u, 0u, 0u};
  if (t < 128) {
    int gg = grow0 + t;
    qv = Qarr[gg];
    fprev = FG2[gg];
    ar = AREC[gg];
  }
  float m = softmax_max128L(grow0, AREC, BIN, Blds, lm);
  if (t < 128) {
    float f_t = qv - 2.0f * m;
    float fo = 0.5f * (fprev + f_t);
    float hs = 0.5f * (fo - qv - EPS1LNM);
    BOUT[grow0 + t] = (uint4){ar.x, ar.y, ar.z, pkh2(hs, 0.0f)};
  }
}

// ==== KC: eps1 softmin pair-4 + dynamic last-block collector ===============
__global__ __launch_bounds__(512) void kc_sm2(
    const uint4* __restrict__ AREC, const uint4* __restrict__ BIN,
    const float* __restrict__ Qarr, float* __restrict__ PART,
    unsigned* __restrict__ BARC, float* __restrict__ out) {
  __shared__ uint4 Blds[4096];
  __shared__ float lm[8][64];
  __shared__ float fsh[128];
  __shared__ float fred[8];
  __shared__ int lastf;
  int t = threadIdx.x;
  int wave = t >> 6, lane = t & 63;
  int grow0 = xcd_rowgrp(blockIdx.x) * 128;
  float qv = 0.0f;
  if (t < 128) qv = Qarr[grow0 + t];
  float m = softmax_max128L(grow0, AREC, BIN, Blds, lm);
  if (t < 128) fsh[t] = qv - 2.0f * m;
  __syncthreads();
  if (t == 0) {
    float ssum = 0.0f;
#pragma unroll
    for (int k = 0; k < 128; ++k) ssum += fsh[k];
    __hip_atomic_store(&PART[blockIdx.x], ssum, __ATOMIC_RELAXED,
                       __HIP_MEMORY_SCOPE_AGENT);
    unsigned old = __hip_atomic_fetch_add(BARC, 1u, __ATOMIC_ACQ_REL,
                                          __HIP_MEMORY_SCOPE_AGENT);
    lastf = (old == (unsigned)(NSM_BLK - 1)) ? 1 : 0;
  }
  __syncthreads();
  if (lastf) {  // block-uniform: only the final arriver sums and writes out
    float a = 0.0f;
    if (t < NSM_BLK)
      a = __hip_atomic_load(&PART[t], __ATOMIC_RELAXED,
                            __HIP_MEMORY_SCOPE_AGENT);
#pragma unroll
    for (int off = 32; off > 0; off >>= 1) a += __shfl_xor(a, off);
    if (lane == 0) fred[wave] = a;
    __syncthreads();
    if (t == 0) {
      float s8 = 0.0f;
#pragma unroll
      for (int k = 0; k < 8; ++k) s8 += fred[k];
      out[0] = s8 * (10.0f / (float)ROWS);
    }
  }
}

extern "C" void kernel_launch(void* const* d_in, const int* in_sizes, int n_in,
                              void* d_out, int out_size, void* d_ws,
                              size_t ws_size, hipStream_t stream) {
  const float* x = (const float*)d_in[0];
  const float* y = (const float*)d_in[1];
  float* out = (float*)d_out;
  float* w = (float*)d_ws;

  unsigned* BARC = (unsigned*)w;
  float* base = w + 16384;
  uint4* AREC  = (uint4*)base;
  uint4* BRECA = AREC + PTS_TOTAL;
  uint4* BRECB = BRECA + PTS_TOTAL;
  float* Qarr  = base + 3 * 4 * PTS_TOTAL;
  float* FG2   = Qarr + PTS_TOTAL;
  float* FG1   = FG2 + PTS_TOTAL;
  float* PART  = FG1 + PTS_TOTAL;

  (void)ws_size;
  k1_max<<<128, 256, 0, stream>>>(x, y, w);
  k2_pack<<<128, 256, 0, stream>>>(x, y, w);
  k3_rows1<<<128, 256, 0, stream>>>(x, y, w);
  k4_rows2<<<128, 256, 0, stream>>>(x, y, w);
  kb_sm1<<<NSM_BLK, 512, 0, stream>>>(AREC, BRECA, BRECB, Qarr, FG2);
  kc_sm2<<<NSM_BLK, 512, 0, stream>>>(AREC, BRECB, Qarr, PART, BARC, out);
}